// Round 3
// baseline (1532.864 us; speedup 1.0000x reference)
//
#include <hip/hip_runtime.h>
#include <hip/hip_bf16.h>

#define NROWS   524288
#define NOPS    12
#define IN_DIM  24
#define HID     256
#define KDIM    288       // 24 (x) + 256 (hidden) + 8 zero pad
#define LDS_STR 320       // shorts per LDS row (640 B; headroom for XOR swizzle)
#define BM      64        // rows per block

typedef __attribute__((ext_vector_type(8))) short bf16x8;
typedef __attribute__((ext_vector_type(4))) float f32x4;

__device__ __forceinline__ short f2bf(float f) {
    // round-to-nearest-even fp32 -> bf16 (no NaN in this data)
    unsigned u = __builtin_bit_cast(unsigned, f);
    u += 0x7FFFu + ((u >> 16) & 1u);
    return (short)(u >> 16);
}
__device__ __forceinline__ float bf2f(short s) {
    unsigned u = ((unsigned)(unsigned short)s) << 16;
    return __builtin_bit_cast(float, u);
}
__device__ __forceinline__ float tanh_fast(float z) {
    // tanh(z) = 1 - 2/(e^{2z}+1); exact at +-inf, abs err ~1e-7
    return 1.f - 2.f / (__expf(2.f * z) + 1.f);
}

// ---------------------------------------------------------------------------
// Prep: pack Wc = [W_ih | W_hh | 0] (256 x 288) into MFMA B-fragment order:
//   w_swz[((nt*9 + kk)*64 + lane)*8 + j] = Wc[nt*16 + (lane&15)][kk*32 + (lane>>4)*8 + j]
// so the main kernel's B-frag load is one coalesced 16B load per lane.
// (Any per-lane k-order works as long as A-frags use the SAME order.)
// Also fuse biases: bsum = b_ih + b_hh.
// ---------------------------------------------------------------------------
extern "C" __global__ __launch_bounds__(256)
void rnn_prep(const float* __restrict__ W_ih, const float* __restrict__ b_ih,
              const float* __restrict__ W_hh, const float* __restrict__ b_hh,
              short* __restrict__ w_swz, float* __restrict__ bsum)
{
    int tid = blockIdx.x * 256 + threadIdx.x;
    if (tid < 16 * 9 * 64) {
        int l  = tid & 63;
        int kk = (tid >> 6) % 9;
        int nt = tid / 576;
        int n  = nt * 16 + (l & 15);
        int k0 = kk * 32 + ((l >> 4) << 3);
        bf16x8 pk;
        #pragma unroll
        for (int j = 0; j < 8; ++j) {
            int k = k0 + j;
            float v = 0.f;
            if (k < 24)       v = W_ih[n * 24 + k];
            else if (k < 280) v = W_hh[n * 256 + (k - 24)];
            pk[j] = f2bf(v);
        }
        reinterpret_cast<bf16x8*>(w_swz)[tid] = pk;
    }
    if (tid < 256) bsum[tid] = b_ih[tid] + b_hh[tid];
}

// ---------------------------------------------------------------------------
// Main: per block of 64 rows -- stage [x|h] bf16 to LDS (XOR-swizzled),
// MFMA z = A @ Wc^T, tanh, store h_new (fp32 global + bf16 LDS), then
// projection (12 ops) + softmax on VALU.
// ---------------------------------------------------------------------------
extern "C" __global__ __launch_bounds__(256)
void rnn_main(const float* __restrict__ x, const float* __restrict__ hidden,
              const bf16x8* __restrict__ wsz, const float* __restrict__ bsum,
              const float* __restrict__ Wp, const float* __restrict__ bp,
              float* __restrict__ out, float* __restrict__ hout)
{
    __shared__ short lds_a[BM * LDS_STR];
    const int t = threadIdx.x;
    const long row0 = (long)blockIdx.x * BM;

    // ---- stage hidden rows (64 x 256 fp32 -> bf16 LDS cols 24..279) ----
    const float4* hsrc = reinterpret_cast<const float4*>(hidden + row0 * HID);
    #pragma unroll
    for (int i = 0; i < 16; ++i) {
        int idx = i * 256 + t;                 // 0..4095 float4s, coalesced
        int r = idx >> 6, c4 = idx & 63;
        float4 v = hsrc[idx];
        int c = 24 + c4 * 4;
        int sidx = r * LDS_STR + (c ^ ((r & 7) << 3));
        short4 pk; pk.x = f2bf(v.x); pk.y = f2bf(v.y); pk.z = f2bf(v.z); pk.w = f2bf(v.w);
        *reinterpret_cast<short4*>(&lds_a[sidx]) = pk;
    }
    // ---- stage x rows (64 x 24 -> LDS cols 0..23) ----
    if (t < 128) {
        const float4* xsrc = reinterpret_cast<const float4*>(x + row0 * IN_DIM);
        #pragma unroll
        for (int i = 0; i < 3; ++i) {
            int idx = i * 128 + t;             // 0..383 float4s
            int r = idx / 6, c4 = idx % 6;
            float4 v = xsrc[idx];
            int c = c4 * 4;
            int sidx = r * LDS_STR + (c ^ ((r & 7) << 3));
            short4 pk; pk.x = f2bf(v.x); pk.y = f2bf(v.y); pk.z = f2bf(v.z); pk.w = f2bf(v.w);
            *reinterpret_cast<short4*>(&lds_a[sidx]) = pk;
        }
    }
    // ---- zero pad cols 280..287 (B is zero there, but LDS garbage could be NaN) ----
    if (t < 64) {
        int r = t;
        int sidx = r * LDS_STR + (280 ^ ((r & 7) << 3));
        bf16x8 z = {};
        *reinterpret_cast<bf16x8*>(&lds_a[sidx]) = z;
    }
    __syncthreads();

    // ---- MFMA: wave wid owns cols [wid*64, wid*64+64), all 64 rows ----
    const int wid  = t >> 6;
    const int l    = t & 63;
    const int lrow = l & 15;              // A row / B col within 16
    const int lk   = (l >> 4) << 3;       // k sub-offset 0/8/16/24
    const int swz  = (lrow & 7) << 3;

    f32x4 acc[4][4] = {};
    #pragma unroll
    for (int kk = 0; kk < 9; ++kk) {
        int k0 = kk * 32 + lk;
        bf16x8 af[4], bfr[4];
        #pragma unroll
        for (int mi = 0; mi < 4; ++mi) {
            int row = mi * 16 + lrow;     // (row&7) == (lrow&7)
            af[mi] = *reinterpret_cast<const bf16x8*>(&lds_a[row * LDS_STR + (k0 ^ swz)]);
        }
        #pragma unroll
        for (int ni = 0; ni < 4; ++ni)
            bfr[ni] = wsz[((wid * 4 + ni) * 9 + kk) * 64 + l];
        #pragma unroll
        for (int mi = 0; mi < 4; ++mi)
            #pragma unroll
            for (int ni = 0; ni < 4; ++ni)
                acc[mi][ni] = __builtin_amdgcn_mfma_f32_16x16x32_bf16(
                    af[mi], bfr[ni], acc[mi][ni], 0, 0, 0);
    }
    __syncthreads();   // all A-tile reads done; lds_a will be reused for h_new

    // ---- bias + tanh; store h_new fp32 to global and bf16 to LDS ----
    float bs[4];
    #pragma unroll
    for (int ni = 0; ni < 4; ++ni) bs[ni] = bsum[wid * 64 + ni * 16 + lrow];

    #pragma unroll
    for (int mi = 0; mi < 4; ++mi) {
        #pragma unroll
        for (int ni = 0; ni < 4; ++ni) {
            int col = wid * 64 + ni * 16 + lrow;
            #pragma unroll
            for (int r = 0; r < 4; ++r) {
                int m = mi * 16 + (l >> 4) * 4 + r;   // C/D layout: col=lane&15, row=(lane>>4)*4+reg
                float h = tanh_fast(acc[mi][ni][r] + bs[ni]);
                hout[(row0 + m) * HID + col] = h;
                lds_a[m * LDS_STR + (col ^ ((m & 7) << 3))] = f2bf(h);
            }
        }
    }
    __syncthreads();

    // ---- projection (256 -> 12) + softmax; 4 threads per row, 3 ops each ----
    {
        const int prow = t >> 2;              // 0..63
        const int pg   = t & 3;
        const int p0   = pg * 3;
        const int swzp = (prow & 7) << 3;
        const float* w0 = Wp + (p0 + 0) * HID;
        const float* w1 = Wp + (p0 + 1) * HID;
        const float* w2 = Wp + (p0 + 2) * HID;
        float a0 = 0.f, a1 = 0.f, a2 = 0.f;
        #pragma unroll 4
        for (int c0 = 0; c0 < HID; c0 += 8) {
            bf16x8 hv = *reinterpret_cast<const bf16x8*>(
                &lds_a[prow * LDS_STR + (c0 ^ swzp)]);
            float hf[8];
            #pragma unroll
            for (int j = 0; j < 8; ++j) hf[j] = bf2f(hv[j]);
            float4 wa, wb;
            wa = *reinterpret_cast<const float4*>(&w0[c0]);
            wb = *reinterpret_cast<const float4*>(&w0[c0 + 4]);
            a0 += hf[0]*wa.x + hf[1]*wa.y + hf[2]*wa.z + hf[3]*wa.w
                + hf[4]*wb.x + hf[5]*wb.y + hf[6]*wb.z + hf[7]*wb.w;
            wa = *reinterpret_cast<const float4*>(&w1[c0]);
            wb = *reinterpret_cast<const float4*>(&w1[c0 + 4]);
            a1 += hf[0]*wa.x + hf[1]*wa.y + hf[2]*wa.z + hf[3]*wa.w
                + hf[4]*wb.x + hf[5]*wb.y + hf[6]*wb.z + hf[7]*wb.w;
            wa = *reinterpret_cast<const float4*>(&w2[c0]);
            wb = *reinterpret_cast<const float4*>(&w2[c0 + 4]);
            a2 += hf[0]*wa.x + hf[1]*wa.y + hf[2]*wa.z + hf[3]*wa.w
                + hf[4]*wb.x + hf[5]*wb.y + hf[6]*wb.z + hf[7]*wb.w;
        }
        a0 += bp[p0]; a1 += bp[p0 + 1]; a2 += bp[p0 + 2];

        float mx = fmaxf(a0, fmaxf(a1, a2));
        mx = fmaxf(mx, __shfl_xor(mx, 1));
        mx = fmaxf(mx, __shfl_xor(mx, 2));
        float e0 = __expf(a0 - mx), e1 = __expf(a1 - mx), e2 = __expf(a2 - mx);
        float s = e0 + e1 + e2;
        s += __shfl_xor(s, 1);
        s += __shfl_xor(s, 2);
        float inv = 1.f / s;
        float* op = out + (row0 + prow) * NOPS + p0;
        op[0] = e0 * inv; op[1] = e1 * inv; op[2] = e2 * inv;
    }
}

// ---------------------------------------------------------------------------
extern "C" void kernel_launch(void* const* d_in, const int* in_sizes, int n_in,
                              void* d_out, int out_size, void* d_ws, size_t ws_size,
                              hipStream_t stream)
{
    const float* x      = (const float*)d_in[0];
    const float* hidden = (const float*)d_in[1];
    const float* W_ih   = (const float*)d_in[2];
    const float* b_ih   = (const float*)d_in[3];
    const float* W_hh   = (const float*)d_in[4];
    const float* b_hh   = (const float*)d_in[5];
    const float* W_proj = (const float*)d_in[6];
    const float* b_proj = (const float*)d_in[7];

    float* out  = (float*)d_out;
    float* hout = out + (size_t)NROWS * NOPS;   // tuple: (out, h_new) concatenated

    short* w_swz = (short*)d_ws;                            // 16*9*64*8 bf16 = 147456 B
    float* bsum  = (float*)((char*)d_ws + 16 * 9 * 64 * 8 * sizeof(short));

    hipLaunchKernelGGL(rnn_prep, dim3(37), dim3(256), 0, stream,
                       W_ih, b_ih, W_hh, b_hh, w_swz, bsum);
    hipLaunchKernelGGL(rnn_main, dim3(NROWS / BM), dim3(256), 0, stream,
                       x, hidden, (const bf16x8*)w_swz, bsum, W_proj, b_proj, out, hout);
}